// Round 12
// baseline (753.587 us; speedup 1.0000x reference)
//
#include <hip/hip_runtime.h>

// RelativeLearnableAttention — MI355X (round 17)
// B=4 N=2048 DIM=256 H=8 D=32, scale = 1/16.
// Contract: inputs f32, mask int32, d_out = f32 (out [4,2048,256] ++ attn [4,8,2048,2048]).
// R17: kattn1 occupancy 50% -> ~100% without R9's traps:
//  - grid 2048 x 256thr: block = (bh, it2) covers 32 rows; 4 waves = 2 i-subtiles
//    x 2 j-halves (wid: iw=wid&1, jh=wid>>1). 8 blocks/CU x 4 waves = 32 waves/CU.
//  - __launch_bounds__(256,8): kattn1-only body (~50 persistent VGPR, vs fused 56
//    measured) fits the 64-VGPR cap; R9's fail was 512-thr + fused body.
//  - mask from GLOBAL (L2-resident 8KB, hidden by 8-wave TLP) -> LDS = pbuf only
//    (18.4KB/block -> 8 blocks/CU = 147KB < 160KB).
//  - partial l / O combined across j-half pairs (wid^2) via LDS aliased on dead
//    pbuf (R9-validated algebra; masked rows: 1024+1024 = 2048 ok).
// Everything else identical to R16 (752.7us validated).

typedef short bf16x8 __attribute__((ext_vector_type(8)));
typedef float f32x4  __attribute__((ext_vector_type(4)));

static __device__ __forceinline__ unsigned short f2b(float f) {
    union { float f; unsigned int u; } x; x.f = f;
    unsigned int r = x.u + 0x7fffu + ((x.u >> 16) & 1u);   // RNE
    return (unsigned short)(r >> 16);
}

static __device__ __forceinline__ float exp2_fast(float x) {
    float r;
    asm("v_exp_f32 %0, %1" : "=v"(r) : "v"(x));   // D = 2^S0
    return r;
}

// ---------------------------------------------------------------------------
// Prep: f32->bf16 of w, r; transpose+convert Wqkv/Wr/Wout; mask -> mwf[b][i]
// as FLOAT 0/1 (left-pad True). ~12 MB traffic.
__global__ __launch_bounds__(256) void kprep(
    const float* __restrict__ w, const float* __restrict__ r,
    const float* __restrict__ Wqkv, const float* __restrict__ Wr,
    const float* __restrict__ Wout, const int* __restrict__ amask,
    unsigned short* __restrict__ wb, unsigned short* __restrict__ rb,
    unsigned short* __restrict__ WqkvT, unsigned short* __restrict__ WrT,
    unsigned short* __restrict__ WoutT, float* __restrict__ mwf)
{
    int o = blockIdx.x * 256 + threadIdx.x;
    if (o < 2097152) { wb[o] = f2b(w[o]); return; }
    o -= 2097152;
    if (o < 524288) { rb[o] = f2b(r[o]); return; }
    o -= 524288;
    if (o < 196608) { int n = o >> 8, k = o & 255; WqkvT[o] = f2b(Wqkv[k * 768 + n]); return; }
    o -= 196608;
    if (o < 65536) { int n = o >> 8, k = o & 255; WrT[o] = f2b(Wr[k * 256 + n]); return; }
    o -= 65536;
    if (o < 65536) { int n = o >> 8, k = o & 255; WoutT[o] = f2b(Wout[k * 256 + n]); return; }
    o -= 65536;
    if (o < 8192) {
        const int b = o >> 11, i = o & 2047;
        mwf[o] = (i == 0 || amask[b * 2047 + i - 1] != 0) ? 1.0f : 0.0f;
    }
}

// ---------------------------------------------------------------------------
// QKV GEMM: [8192x256] @ [256x768]; epilogue splits q/k/v, adds f32 biases to q,
// writes q1=(q+r_w_bias)*CS, q2=(q+r_r_bias)*CS (CS = scale*log2e folded so the
// attention kernels use raw v_exp_f32), k as [bh][n][32], v transposed [bh][32][n].
__global__ __launch_bounds__(256) void kqkv(
    const unsigned short* __restrict__ w,      // [8192][256] bf16
    const unsigned short* __restrict__ WqkvT,  // [768][256] bf16
    const float* __restrict__ rwb,             // [256] f32 (h*32+d)
    const float* __restrict__ rrb,             // [256] f32
    unsigned short* __restrict__ q1w,          // [32][2048][32]
    unsigned short* __restrict__ q2w,
    unsigned short* __restrict__ kw,           // [32][2048][32]
    unsigned short* __restrict__ vTw)          // [32][32][2048]
{
    const int m0 = blockIdx.x * 64;
    const int n0 = blockIdx.y * 64;
    const int tid = threadIdx.x;
    const int wid = tid >> 6, lane = tid & 63;
    const int l16 = lane & 15, quad = lane >> 4;

    const float CS = 0.09016844f;   // (1/16) * log2(e)

    f32x4 acc[4] = {};
    const unsigned short* arow = w + (m0 + wid * 16 + l16) * 256 + quad * 8;
    for (int kc = 0; kc < 8; ++kc) {
        bf16x8 aF = *(const bf16x8*)(arow + kc * 32);
#pragma unroll
        for (int t = 0; t < 4; ++t) {
            bf16x8 bF = *(const bf16x8*)(WqkvT + (n0 + t * 16 + l16) * 256 + kc * 32 + quad * 8);
            acc[t] = __builtin_amdgcn_mfma_f32_16x16x32_bf16(aF, bF, acc[t], 0, 0, 0);
        }
    }
#pragma unroll
    for (int t = 0; t < 4; ++t) {
        const int cbase = n0 + t * 16;        // wave-uniform; never straddles a section/head
        const int sect = cbase >> 8;          // 0=q 1=k 2=v
        const int h = (cbase & 255) >> 5;
        const int d = (cbase & 31) + l16;
        const int m = m0 + wid * 16 + quad * 4;
        const int b = m >> 11;
        const int n = m & 2047;
        const int bh = b * 8 + h;
        if (sect == 0) {
            const float bw = rwb[h * 32 + d];
            const float br = rrb[h * 32 + d];
#pragma unroll
            for (int rr = 0; rr < 4; ++rr) {
                int idx = (bh * 2048 + n + rr) * 32 + d;
                q1w[idx] = f2b((acc[t][rr] + bw) * CS);
                q2w[idx] = f2b((acc[t][rr] + br) * CS);
            }
        } else if (sect == 1) {
#pragma unroll
            for (int rr = 0; rr < 4; ++rr)
                kw[(bh * 2048 + n + rr) * 32 + d] = f2b(acc[t][rr]);
        } else {
            ushort4 u;
            u.x = f2b(acc[t][0]); u.y = f2b(acc[t][1]);
            u.z = f2b(acc[t][2]); u.w = f2b(acc[t][3]);
            *(ushort4*)(vTw + (bh * 32 + d) * 2048 + n) = u;   // n is 4-aligned
        }
    }
}

// ---------------------------------------------------------------------------
// [Mx256] @ [256x256] bf16 GEMM, bf16 output (internal: r@Wr).
__global__ __launch_bounds__(256) void kgemm256b(
    const unsigned short* __restrict__ A, const unsigned short* __restrict__ BT,
    unsigned short* __restrict__ C)
{
    const int m0 = blockIdx.x * 64;
    const int n0 = blockIdx.y * 64;
    const int tid = threadIdx.x;
    const int wid = tid >> 6, lane = tid & 63;
    const int l16 = lane & 15, quad = lane >> 4;

    f32x4 acc[4] = {};
    const unsigned short* arow = A + (m0 + wid * 16 + l16) * 256 + quad * 8;
    for (int kc = 0; kc < 8; ++kc) {
        bf16x8 aF = *(const bf16x8*)(arow + kc * 32);
#pragma unroll
        for (int t = 0; t < 4; ++t) {
            bf16x8 bF = *(const bf16x8*)(BT + (n0 + t * 16 + l16) * 256 + kc * 32 + quad * 8);
            acc[t] = __builtin_amdgcn_mfma_f32_16x16x32_bf16(aF, bF, acc[t], 0, 0, 0);
        }
    }
#pragma unroll
    for (int t = 0; t < 4; ++t) {
        const int c = n0 + t * 16 + l16;
        const int m = m0 + wid * 16 + quad * 4;
#pragma unroll
        for (int rr = 0; rr < 4; ++rr)
            C[(m + rr) * 256 + c] = f2b(acc[t][rr]);
    }
}

// ---------------------------------------------------------------------------
// [Mx256] @ [256x256] bf16 GEMM, FLOAT32 output (final: ctx@Wout -> d_out).
__global__ __launch_bounds__(256) void kgemm256f(
    const unsigned short* __restrict__ A, const unsigned short* __restrict__ BT,
    float* __restrict__ C)
{
    const int m0 = blockIdx.x * 64;
    const int n0 = blockIdx.y * 64;
    const int tid = threadIdx.x;
    const int wid = tid >> 6, lane = tid & 63;
    const int l16 = lane & 15, quad = lane >> 4;

    f32x4 acc[4] = {};
    const unsigned short* arow = A + (m0 + wid * 16 + l16) * 256 + quad * 8;
    for (int kc = 0; kc < 8; ++kc) {
        bf16x8 aF = *(const bf16x8*)(arow + kc * 32);
#pragma unroll
        for (int t = 0; t < 4; ++t) {
            bf16x8 bF = *(const bf16x8*)(BT + (n0 + t * 16 + l16) * 256 + kc * 32 + quad * 8);
            acc[t] = __builtin_amdgcn_mfma_f32_16x16x32_bf16(aF, bF, acc[t], 0, 0, 0);
        }
    }
#pragma unroll
    for (int t = 0; t < 4; ++t) {
        const int c = n0 + t * 16 + l16;
        const int m = m0 + wid * 16 + quad * 4;
#pragma unroll
        for (int rr = 0; rr < 4; ++rr)
            C[(m + rr) * 256 + c] = acc[t][rr];
    }
}

// ---------------------------------------------------------------------------
// kattn1: softmax denominators + PV context. NO attn stores.
// Block covers 32 rows; 4 waves = 2 i-subtiles (iw) x 2 j-halves (jh).
// Each wave: 16 rows x 16 j-tiles (1024 cols). Partial l and O combined across
// j-half pairs (wid^2) via LDS aliased on dead pbuf. Mask read from global
// (L2-resident, hidden by 8-wave TLP). 8 blocks/CU -> 32 waves/CU.
// Fully-masked rows: p=1 forall j -> l = 1024+1024 = 2048 (matches reference).
__global__ __launch_bounds__(256, 8) void kattn1(
    const unsigned short* __restrict__ q1w,  // [32][2048][32]
    const unsigned short* __restrict__ q2w,
    const unsigned short* __restrict__ kw,   // [32][2048][32]
    const unsigned short* __restrict__ vTw,  // [32][32][2048]
    const unsigned short* __restrict__ rr,   // flat [8][2048][32]
    const float* __restrict__ mwf,           // [4][2048] f32 0/1
    float* __restrict__ invl_ws,             // [32][2048] f32
    unsigned short* __restrict__ ctx)        // [4][2048][256] bf16
{
    __shared__ __align__(16) unsigned short pbuf[4][2][16][72];  // 18.4 KB

    // bh-clustered XCD swizzle: XCD x owns bh 4x..4x+3 (64 blocks each)
    const int blk = blockIdx.x;              // 2048 = 32 bh * 64 it2(32-row)
    const int xcd = blk & 7, idx = blk >> 3; // idx in [0,256)
    const int bh = xcd * 4 + (idx >> 6);
    const int it2 = idx & 63;
    const int b = bh >> 3, h = bh & 7;
    const int tid = threadIdx.x;
    const int wid = tid >> 6, lane = tid & 63;
    const int iw = wid & 1, jh = wid >> 1;
    const int l16 = lane & 15, quad = lane >> 4;
    const int i0 = it2 * 32 + iw * 16;
    const int jt0 = jh * 16, jt1 = jt0 + 16;

    const bf16x8 a1 = *(const bf16x8*)(q1w + (bh * 2048 + i0 + l16) * 32 + quad * 8);
    const bf16x8 a2 = *(const bf16x8*)(q2w + (bh * 2048 + i0 + l16) * 32 + quad * 8);

    const float* mwb = mwf + b * 2048;
    float mi[4];
#pragma unroll
    for (int r = 0; r < 4; ++r)
        mi[r] = mwb[i0 + quad * 4 + r];

    const unsigned short* kbase = kw + bh * 2048 * 32;
    const unsigned short* rbase = rr + h * 65536;
    const unsigned short* vbase = vTw + bh * 32 * 2048;

    float lsum[4] = {0.f, 0.f, 0.f, 0.f};
    f32x4 oacc[2] = {};

    // ---- pass A: partial l + partial PV over own j-half ----
    for (int jt = jt0; jt < jt1; ++jt) {
        const int j0 = jt * 64;
        unsigned short (*pb)[72] = pbuf[wid][jt & 1];
        f32x4 s[4];
#pragma unroll
        for (int t = 0; t < 4; ++t) {
            bf16x8 bK = *(const bf16x8*)(kbase + (j0 + t * 16 + l16) * 32 + quad * 8);
            bf16x8 bR = *(const bf16x8*)(rbase + (j0 + t * 16 + l16) * 32 + quad * 8);
            f32x4 z = {};
            z = __builtin_amdgcn_mfma_f32_16x16x32_bf16(a1, bK, z, 0, 0, 0);
            s[t] = __builtin_amdgcn_mfma_f32_16x16x32_bf16(a2, bR, z, 0, 0, 0);
        }
#pragma unroll
        for (int t = 0; t < 4; ++t) {
            const float mj = mwb[j0 + t * 16 + l16];   // L2-hot global read
#pragma unroll
            for (int r = 0; r < 4; ++r) {
                float p = (mi[r] == 0.f) ? 1.f : exp2_fast(s[t][r]) * mj;
                lsum[r] += p;
                pb[quad * 4 + r][t * 16 + l16] = f2b(p);
            }
        }
        // Cross-lane dep: lanes read rows other lanes wrote. One ordering
        // point per tile (double buffer covers the WAR side).
        asm volatile("s_waitcnt lgkmcnt(0)" ::: "memory");
#pragma unroll
        for (int kc = 0; kc < 2; ++kc) {
            bf16x8 pA = *(const bf16x8*)(&pb[l16][kc * 32 + quad * 8]);
#pragma unroll
            for (int dt = 0; dt < 2; ++dt) {
                bf16x8 bV = *(const bf16x8*)(vbase + (dt * 16 + l16) * 2048 + j0 + kc * 32 + quad * 8);
                oacc[dt] = __builtin_amdgcn_mfma_f32_16x16x32_bf16(pA, bV, oacc[dt], 0, 0, 0);
            }
        }
    }

    // ---- in-wave reduce: sum across the 16 lanes of each quad-group ----
    float vrow[4];
#pragma unroll
    for (int r = 0; r < 4; ++r) {
        float v = lsum[r];
        v += __shfl_xor(v, 1);
        v += __shfl_xor(v, 2);
        v += __shfl_xor(v, 4);
        v += __shfl_xor(v, 8);
        vrow[r] = v;   // half-row total; identical across the 16-lane group
    }

    // ---- cross-wave combine (partner = wid^2) via LDS aliased on pbuf ----
    __syncthreads();                                   // pbuf dead from here
    float* lred = (float*)&pbuf[0][0][0][0];           // [4][16] f32 = 256B
    float* ored = lred + 64;                           // [2][64][8] f32 = 4KB
    if (l16 == 0) {
#pragma unroll
        for (int r = 0; r < 4; ++r)
            lred[wid * 16 + quad * 4 + r] = vrow[r];
    }
    if (jh == 1) {
#pragma unroll
        for (int dt = 0; dt < 2; ++dt)
#pragma unroll
            for (int r = 0; r < 4; ++r)
                ored[(iw * 64 + lane) * 8 + dt * 4 + r] = oacc[dt][r];
    }
    __syncthreads();

    if (jh == 0) {
        float invl[4];
#pragma unroll
        for (int r = 0; r < 4; ++r)
            invl[r] = 1.0f / (vrow[r] + lred[(wid ^ 2) * 16 + quad * 4 + r]);
#pragma unroll
        for (int dt = 0; dt < 2; ++dt)
#pragma unroll
            for (int r = 0; r < 4; ++r)
                oacc[dt][r] += ored[(iw * 64 + lane) * 8 + dt * 4 + r];

        if (l16 == 0) {
#pragma unroll
            for (int r = 0; r < 4; ++r)
                invl_ws[bh * 2048 + i0 + quad * 4 + r] = invl[r];
        }
#pragma unroll
        for (int dt = 0; dt < 2; ++dt)
#pragma unroll
            for (int r = 0; r < 4; ++r) {
                float o = oacc[dt][r] * invl[r];
                ctx[(b * 2048 + i0 + quad * 4 + r) * 256 + h * 32 + dt * 16 + l16] = f2b(o);
            }
    }
}

// ---------------------------------------------------------------------------
// kattn2: pure streaming attn writer. Recompute scores, scale by invl, store.
// Grid 2048 blocks = (bh, i-tile 64, j-half 1024); 4 waves x 16 rows x 16 jt.
// No LDS cross-lane dep, no barriers -> compiler pipelines freely.
// 8192 waves = 100% occupancy (launch_bounds(256,8); lean body << 64 VGPR).
__global__ __launch_bounds__(256, 8) void kattn2(
    const unsigned short* __restrict__ q1w,  // [32][2048][32]
    const unsigned short* __restrict__ q2w,
    const unsigned short* __restrict__ kw,   // [32][2048][32]
    const unsigned short* __restrict__ rr,   // flat [8][2048][32]
    const float* __restrict__ mwf,           // [4][2048] f32 0/1
    const float* __restrict__ invl_ws,       // [32][2048] f32
    float* __restrict__ attn)                // [32][2048][2048] f32
{
    __shared__ __align__(16) float msk[1024];   // 4 KB (j-half mask)

    // bh-clustered XCD swizzle: XCD x owns bh 4x..4x+3 (256 blocks each)
    const int blk = blockIdx.x;              // 2048 = 32 bh * 32 it * 2 jh
    const int idx = blk >> 3;                // [0,256)
    const int bh = ((blk & 7) << 2) | (idx >> 6);
    const int rem = idx & 63;
    const int it = rem >> 1, jh = rem & 1;
    const int b = bh >> 3, h = bh & 7;
    const int tid = threadIdx.x;
    const int wid = tid >> 6, lane = tid & 63;
    const int l16 = lane & 15, quad = lane >> 4;
    const int i0 = it * 64 + wid * 16;
    const int jbase = jh * 1024;

    // stage j-half mask: 256 threads x 4
    *(f32x4*)&msk[tid * 4] = *(const f32x4*)(mwf + b * 2048 + jbase + tid * 4);
    __syncthreads();

    const bf16x8 a1 = *(const bf16x8*)(q1w + (bh * 2048 + i0 + l16) * 32 + quad * 8);
    const bf16x8 a2 = *(const bf16x8*)(q2w + (bh * 2048 + i0 + l16) * 32 + quad * 8);

    float scl[4], add[4];
#pragma unroll
    for (int r = 0; r < 4; ++r) {
        const int row = i0 + quad * 4 + r;
        const float iv = invl_ws[bh * 2048 + row];
        const float mi = mwf[b * 2048 + row];
        scl[r] = (mi == 0.f) ? 0.f : iv;   // v = exp2(s)*mj*scl + add
        add[r] = (mi == 0.f) ? iv  : 0.f;  // masked row -> uniform invl (=1/2048)
    }

    const unsigned short* kbase = kw + bh * 2048 * 32;
    const unsigned short* rbase = rr + h * 65536;
    float* abase = attn + (bh * 2048 + i0) * 2048;

    for (int jt = 0; jt < 16; ++jt) {
        const int jl = jt * 64;              // offset within j-half
        const int j0 = jbase + jl;           // global j
        f32x4 s[4];
#pragma unroll
        for (int t = 0; t < 4; ++t) {
            bf16x8 bK = *(const bf16x8*)(kbase + (j0 + t * 16 + l16) * 32 + quad * 8);
            bf16x8 bR = *(const bf16x8*)(rbase + (j0 + t * 16 + l16) * 32 + quad * 8);
            f32x4 z = {};
            z = __builtin_amdgcn_mfma_f32_16x16x32_bf16(a1, bK, z, 0, 0, 0);
            s[t] = __builtin_amdgcn_mfma_f32_16x16x32_bf16(a2, bR, z, 0, 0, 0);
        }
#pragma unroll
        for (int t = 0; t < 4; ++t) {
            const float mj = msk[jl + t * 16 + l16];
            float* dst = abase + j0 + t * 16 + l16 + (quad * 4) * 2048;
#pragma unroll
            for (int r = 0; r < 4; ++r) {
                float v = exp2_fast(s[t][r]) * mj * scl[r] + add[r];
                dst[r * 2048] = v;
            }
        }
    }
}

// ---------------------------------------------------------------------------
extern "C" void kernel_launch(void* const* d_in, const int* in_sizes, int n_in,
                              void* d_out, int out_size, void* d_ws, size_t ws_size,
                              hipStream_t stream) {
    const float* w    = (const float*)d_in[0];  // [4][2048][256]
    const float* r    = (const float*)d_in[1];  // [2048][256]
    const int*   am   = (const int*)d_in[2];    // [4][2047]
    const float* Wqkv = (const float*)d_in[3];  // [256][768]
    const float* Wr   = (const float*)d_in[4];  // [256][256]
    const float* Wout = (const float*)d_in[5];  // [256][256]
    const float* rwb  = (const float*)d_in[6];  // [8][1][32]
    const float* rrb  = (const float*)d_in[7];  // [8][1][32]

    float* out  = (float*)d_out;                // [4][2048][256] f32
    float* attn = out + 4 * 2048 * 256;         // [4][8][2048][2048] f32

    unsigned short* ws    = (unsigned short*)d_ws;          // ~27 MB scratch
    unsigned short* wb    = ws;                             // 2,097,152
    unsigned short* rb    = wb + 2097152;                   // 524,288
    unsigned short* q1w   = rb + 524288;                    // 2,097,152
    unsigned short* q2w   = q1w + 2097152;
    unsigned short* kw    = q2w + 2097152;
    unsigned short* vTw   = kw + 2097152;
    unsigned short* rrw   = vTw + 2097152;                  // 524,288
    unsigned short* ctx   = rrw + 524288;                   // 2,097,152
    unsigned short* WqkvT = ctx + 2097152;                  // 196,608
    unsigned short* WrT   = WqkvT + 196608;                 // 65,536
    unsigned short* WoutT = WrT + 65536;                    // 65,536
    float*          mwfp  = (float*)(WoutT + 65536);        // 8,192 f32 (32 KB)
    float*          invlp = mwfp + 8192;                    // 65,536 f32 (256 KB)

    kprep    <<<dim3(11552),   dim3(256), 0, stream>>>(w, r, Wqkv, Wr, Wout, am,
                                                       wb, rb, WqkvT, WrT, WoutT, mwfp);
    kqkv     <<<dim3(128, 12), dim3(256), 0, stream>>>(wb, WqkvT, rwb, rrb, q1w, q2w, kw, vTw);
    kgemm256b<<<dim3(32, 4),   dim3(256), 0, stream>>>(rb, WrT, rrw);
    kattn1   <<<dim3(2048),    dim3(256), 0, stream>>>(q1w, q2w, kw, vTw, rrw, mwfp, invlp, ctx);
    kattn2   <<<dim3(2048),    dim3(256), 0, stream>>>(q1w, q2w, kw, rrw, mwfp, invlp, attn);
    kgemm256f<<<dim3(128, 4),  dim3(256), 0, stream>>>(ctx, WoutT, out);
}

// Round 14
// 750.415 us; speedup vs baseline: 1.0042x; 1.0042x over previous
//
#include <hip/hip_runtime.h>

// RelativeLearnableAttention — MI355X (round 19)
// B=4 N=2048 DIM=256 H=8 D=32, scale = 1/16.
// Contract: inputs f32, mask int32, d_out = f32 (out [4,2048,256] ++ attn [4,8,2048,2048]).
// R19: REVERT kattn2 to the R17-validated orientation after R18's transposed-
// score failure (Output 1 absmax 1.01e-2 = full-value j-permutation). Fifth
// MFMA-operand-remap failure this session (R12/13/14/15/18): formal layout
// derivations keep passing on paper and failing on HW -> per R9 discipline,
// no further MFMA layout changes. This is the validated 753us pipeline:
//   kprep (f32 mask) -> kqkv (CS=scale*log2e folded into q1/q2, k + vT layouts)
//   -> kgemm256b (r@Wr) -> kattn1 (l+PV+ctx; split-j 8 blocks/CU) -> kattn2
//   (streaming attn writer, validated mfma(Q,K) orientation) -> kgemm256f.

typedef short bf16x8 __attribute__((ext_vector_type(8)));
typedef float f32x4  __attribute__((ext_vector_type(4)));

static __device__ __forceinline__ unsigned short f2b(float f) {
    union { float f; unsigned int u; } x; x.f = f;
    unsigned int r = x.u + 0x7fffu + ((x.u >> 16) & 1u);   // RNE
    return (unsigned short)(r >> 16);
}

static __device__ __forceinline__ float exp2_fast(float x) {
    float r;
    asm("v_exp_f32 %0, %1" : "=v"(r) : "v"(x));   // D = 2^S0
    return r;
}

// ---------------------------------------------------------------------------
// Prep: f32->bf16 of w, r; transpose+convert Wqkv/Wr/Wout; mask -> mwf[b][i]
// as FLOAT 0/1 (left-pad True). ~12 MB traffic.
__global__ __launch_bounds__(256) void kprep(
    const float* __restrict__ w, const float* __restrict__ r,
    const float* __restrict__ Wqkv, const float* __restrict__ Wr,
    const float* __restrict__ Wout, const int* __restrict__ amask,
    unsigned short* __restrict__ wb, unsigned short* __restrict__ rb,
    unsigned short* __restrict__ WqkvT, unsigned short* __restrict__ WrT,
    unsigned short* __restrict__ WoutT, float* __restrict__ mwf)
{
    int o = blockIdx.x * 256 + threadIdx.x;
    if (o < 2097152) { wb[o] = f2b(w[o]); return; }
    o -= 2097152;
    if (o < 524288) { rb[o] = f2b(r[o]); return; }
    o -= 524288;
    if (o < 196608) { int n = o >> 8, k = o & 255; WqkvT[o] = f2b(Wqkv[k * 768 + n]); return; }
    o -= 196608;
    if (o < 65536) { int n = o >> 8, k = o & 255; WrT[o] = f2b(Wr[k * 256 + n]); return; }
    o -= 65536;
    if (o < 65536) { int n = o >> 8, k = o & 255; WoutT[o] = f2b(Wout[k * 256 + n]); return; }
    o -= 65536;
    if (o < 8192) {
        const int b = o >> 11, i = o & 2047;
        mwf[o] = (i == 0 || amask[b * 2047 + i - 1] != 0) ? 1.0f : 0.0f;
    }
}

// ---------------------------------------------------------------------------
// QKV GEMM: [8192x256] @ [256x768]; epilogue splits q/k/v, adds f32 biases to q,
// writes q1=(q+r_w_bias)*CS, q2=(q+r_r_bias)*CS (CS = scale*log2e folded so the
// attention kernels use raw v_exp_f32), k as [bh][n][32], v transposed [bh][32][n].
__global__ __launch_bounds__(256) void kqkv(
    const unsigned short* __restrict__ w,      // [8192][256] bf16
    const unsigned short* __restrict__ WqkvT,  // [768][256] bf16
    const float* __restrict__ rwb,             // [256] f32 (h*32+d)
    const float* __restrict__ rrb,             // [256] f32
    unsigned short* __restrict__ q1w,          // [32][2048][32]
    unsigned short* __restrict__ q2w,
    unsigned short* __restrict__ kw,           // [32][2048][32]
    unsigned short* __restrict__ vTw)          // [32][32][2048]
{
    const int m0 = blockIdx.x * 64;
    const int n0 = blockIdx.y * 64;
    const int tid = threadIdx.x;
    const int wid = tid >> 6, lane = tid & 63;
    const int l16 = lane & 15, quad = lane >> 4;

    const float CS = 0.09016844f;   // (1/16) * log2(e)

    f32x4 acc[4] = {};
    const unsigned short* arow = w + (m0 + wid * 16 + l16) * 256 + quad * 8;
    for (int kc = 0; kc < 8; ++kc) {
        bf16x8 aF = *(const bf16x8*)(arow + kc * 32);
#pragma unroll
        for (int t = 0; t < 4; ++t) {
            bf16x8 bF = *(const bf16x8*)(WqkvT + (n0 + t * 16 + l16) * 256 + kc * 32 + quad * 8);
            acc[t] = __builtin_amdgcn_mfma_f32_16x16x32_bf16(aF, bF, acc[t], 0, 0, 0);
        }
    }
#pragma unroll
    for (int t = 0; t < 4; ++t) {
        const int cbase = n0 + t * 16;        // wave-uniform; never straddles a section/head
        const int sect = cbase >> 8;          // 0=q 1=k 2=v
        const int h = (cbase & 255) >> 5;
        const int d = (cbase & 31) + l16;
        const int m = m0 + wid * 16 + quad * 4;
        const int b = m >> 11;
        const int n = m & 2047;
        const int bh = b * 8 + h;
        if (sect == 0) {
            const float bw = rwb[h * 32 + d];
            const float br = rrb[h * 32 + d];
#pragma unroll
            for (int rr = 0; rr < 4; ++rr) {
                int idx = (bh * 2048 + n + rr) * 32 + d;
                q1w[idx] = f2b((acc[t][rr] + bw) * CS);
                q2w[idx] = f2b((acc[t][rr] + br) * CS);
            }
        } else if (sect == 1) {
#pragma unroll
            for (int rr = 0; rr < 4; ++rr)
                kw[(bh * 2048 + n + rr) * 32 + d] = f2b(acc[t][rr]);
        } else {
            ushort4 u;
            u.x = f2b(acc[t][0]); u.y = f2b(acc[t][1]);
            u.z = f2b(acc[t][2]); u.w = f2b(acc[t][3]);
            *(ushort4*)(vTw + (bh * 32 + d) * 2048 + n) = u;   // n is 4-aligned
        }
    }
}

// ---------------------------------------------------------------------------
// [Mx256] @ [256x256] bf16 GEMM, bf16 output (internal: r@Wr).
__global__ __launch_bounds__(256) void kgemm256b(
    const unsigned short* __restrict__ A, const unsigned short* __restrict__ BT,
    unsigned short* __restrict__ C)
{
    const int m0 = blockIdx.x * 64;
    const int n0 = blockIdx.y * 64;
    const int tid = threadIdx.x;
    const int wid = tid >> 6, lane = tid & 63;
    const int l16 = lane & 15, quad = lane >> 4;

    f32x4 acc[4] = {};
    const unsigned short* arow = A + (m0 + wid * 16 + l16) * 256 + quad * 8;
    for (int kc = 0; kc < 8; ++kc) {
        bf16x8 aF = *(const bf16x8*)(arow + kc * 32);
#pragma unroll
        for (int t = 0; t < 4; ++t) {
            bf16x8 bF = *(const bf16x8*)(BT + (n0 + t * 16 + l16) * 256 + kc * 32 + quad * 8);
            acc[t] = __builtin_amdgcn_mfma_f32_16x16x32_bf16(aF, bF, acc[t], 0, 0, 0);
        }
    }
#pragma unroll
    for (int t = 0; t < 4; ++t) {
        const int c = n0 + t * 16 + l16;
        const int m = m0 + wid * 16 + quad * 4;
#pragma unroll
        for (int rr = 0; rr < 4; ++rr)
            C[(m + rr) * 256 + c] = f2b(acc[t][rr]);
    }
}

// ---------------------------------------------------------------------------
// [Mx256] @ [256x256] bf16 GEMM, FLOAT32 output (final: ctx@Wout -> d_out).
__global__ __launch_bounds__(256) void kgemm256f(
    const unsigned short* __restrict__ A, const unsigned short* __restrict__ BT,
    float* __restrict__ C)
{
    const int m0 = blockIdx.x * 64;
    const int n0 = blockIdx.y * 64;
    const int tid = threadIdx.x;
    const int wid = tid >> 6, lane = tid & 63;
    const int l16 = lane & 15, quad = lane >> 4;

    f32x4 acc[4] = {};
    const unsigned short* arow = A + (m0 + wid * 16 + l16) * 256 + quad * 8;
    for (int kc = 0; kc < 8; ++kc) {
        bf16x8 aF = *(const bf16x8*)(arow + kc * 32);
#pragma unroll
        for (int t = 0; t < 4; ++t) {
            bf16x8 bF = *(const bf16x8*)(BT + (n0 + t * 16 + l16) * 256 + kc * 32 + quad * 8);
            acc[t] = __builtin_amdgcn_mfma_f32_16x16x32_bf16(aF, bF, acc[t], 0, 0, 0);
        }
    }
#pragma unroll
    for (int t = 0; t < 4; ++t) {
        const int c = n0 + t * 16 + l16;
        const int m = m0 + wid * 16 + quad * 4;
#pragma unroll
        for (int rr = 0; rr < 4; ++rr)
            C[(m + rr) * 256 + c] = acc[t][rr];
    }
}

// ---------------------------------------------------------------------------
// kattn1: softmax denominators + PV context. NO attn stores. (R17-validated.)
// Block covers 32 rows; 4 waves = 2 i-subtiles (iw) x 2 j-halves (jh).
// Partial l / O combined across j-half pairs (wid^2) via LDS aliased on dead
// pbuf. Mask from global (L2-resident). 8 blocks/CU -> 32 waves/CU.
__global__ __launch_bounds__(256, 8) void kattn1(
    const unsigned short* __restrict__ q1w,  // [32][2048][32]
    const unsigned short* __restrict__ q2w,
    const unsigned short* __restrict__ kw,   // [32][2048][32]
    const unsigned short* __restrict__ vTw,  // [32][32][2048]
    const unsigned short* __restrict__ rr,   // flat [8][2048][32]
    const float* __restrict__ mwf,           // [4][2048] f32 0/1
    float* __restrict__ invl_ws,             // [32][2048] f32
    unsigned short* __restrict__ ctx)        // [4][2048][256] bf16
{
    __shared__ __align__(16) unsigned short pbuf[4][2][16][72];  // 18.4 KB

    // bh-clustered XCD swizzle: XCD x owns bh 4x..4x+3 (64 blocks each)
    const int blk = blockIdx.x;              // 2048 = 32 bh * 64 it2(32-row)
    const int xcd = blk & 7, idx = blk >> 3; // idx in [0,256)
    const int bh = xcd * 4 + (idx >> 6);
    const int it2 = idx & 63;
    const int b = bh >> 3, h = bh & 7;
    const int tid = threadIdx.x;
    const int wid = tid >> 6, lane = tid & 63;
    const int iw = wid & 1, jh = wid >> 1;
    const int l16 = lane & 15, quad = lane >> 4;
    const int i0 = it2 * 32 + iw * 16;
    const int jt0 = jh * 16, jt1 = jt0 + 16;

    const bf16x8 a1 = *(const bf16x8*)(q1w + (bh * 2048 + i0 + l16) * 32 + quad * 8);
    const bf16x8 a2 = *(const bf16x8*)(q2w + (bh * 2048 + i0 + l16) * 32 + quad * 8);

    const float* mwb = mwf + b * 2048;
    float mi[4];
#pragma unroll
    for (int r = 0; r < 4; ++r)
        mi[r] = mwb[i0 + quad * 4 + r];

    const unsigned short* kbase = kw + bh * 2048 * 32;
    const unsigned short* rbase = rr + h * 65536;
    const unsigned short* vbase = vTw + bh * 32 * 2048;

    float lsum[4] = {0.f, 0.f, 0.f, 0.f};
    f32x4 oacc[2] = {};

    // ---- pass A: partial l + partial PV over own j-half ----
    for (int jt = jt0; jt < jt1; ++jt) {
        const int j0 = jt * 64;
        unsigned short (*pb)[72] = pbuf[wid][jt & 1];
        f32x4 s[4];
#pragma unroll
        for (int t = 0; t < 4; ++t) {
            bf16x8 bK = *(const bf16x8*)(kbase + (j0 + t * 16 + l16) * 32 + quad * 8);
            bf16x8 bR = *(const bf16x8*)(rbase + (j0 + t * 16 + l16) * 32 + quad * 8);
            f32x4 z = {};
            z = __builtin_amdgcn_mfma_f32_16x16x32_bf16(a1, bK, z, 0, 0, 0);
            s[t] = __builtin_amdgcn_mfma_f32_16x16x32_bf16(a2, bR, z, 0, 0, 0);
        }
#pragma unroll
        for (int t = 0; t < 4; ++t) {
            const float mj = mwb[j0 + t * 16 + l16];   // L2-hot global read
#pragma unroll
            for (int r = 0; r < 4; ++r) {
                float p = (mi[r] == 0.f) ? 1.f : exp2_fast(s[t][r]) * mj;
                lsum[r] += p;
                pb[quad * 4 + r][t * 16 + l16] = f2b(p);
            }
        }
        // Cross-lane dep: lanes read rows other lanes wrote. One ordering
        // point per tile (double buffer covers the WAR side).
        asm volatile("s_waitcnt lgkmcnt(0)" ::: "memory");
#pragma unroll
        for (int kc = 0; kc < 2; ++kc) {
            bf16x8 pA = *(const bf16x8*)(&pb[l16][kc * 32 + quad * 8]);
#pragma unroll
            for (int dt = 0; dt < 2; ++dt) {
                bf16x8 bV = *(const bf16x8*)(vbase + (dt * 16 + l16) * 2048 + j0 + kc * 32 + quad * 8);
                oacc[dt] = __builtin_amdgcn_mfma_f32_16x16x32_bf16(pA, bV, oacc[dt], 0, 0, 0);
            }
        }
    }

    // ---- in-wave reduce: sum across the 16 lanes of each quad-group ----
    float vrow[4];
#pragma unroll
    for (int r = 0; r < 4; ++r) {
        float v = lsum[r];
        v += __shfl_xor(v, 1);
        v += __shfl_xor(v, 2);
        v += __shfl_xor(v, 4);
        v += __shfl_xor(v, 8);
        vrow[r] = v;   // half-row total; identical across the 16-lane group
    }

    // ---- cross-wave combine (partner = wid^2) via LDS aliased on pbuf ----
    __syncthreads();                                   // pbuf dead from here
    float* lred = (float*)&pbuf[0][0][0][0];           // [4][16] f32 = 256B
    float* ored = lred + 64;                           // [2][64][8] f32 = 4KB
    if (l16 == 0) {
#pragma unroll
        for (int r = 0; r < 4; ++r)
            lred[wid * 16 + quad * 4 + r] = vrow[r];
    }
    if (jh == 1) {
#pragma unroll
        for (int dt = 0; dt < 2; ++dt)
#pragma unroll
            for (int r = 0; r < 4; ++r)
                ored[(iw * 64 + lane) * 8 + dt * 4 + r] = oacc[dt][r];
    }
    __syncthreads();

    if (jh == 0) {
        float invl[4];
#pragma unroll
        for (int r = 0; r < 4; ++r)
            invl[r] = 1.0f / (vrow[r] + lred[(wid ^ 2) * 16 + quad * 4 + r]);
#pragma unroll
        for (int dt = 0; dt < 2; ++dt)
#pragma unroll
            for (int r = 0; r < 4; ++r)
                oacc[dt][r] += ored[(iw * 64 + lane) * 8 + dt * 4 + r];

        if (l16 == 0) {
#pragma unroll
            for (int r = 0; r < 4; ++r)
                invl_ws[bh * 2048 + i0 + quad * 4 + r] = invl[r];
        }
#pragma unroll
        for (int dt = 0; dt < 2; ++dt)
#pragma unroll
            for (int r = 0; r < 4; ++r) {
                float o = oacc[dt][r] * invl[r];
                ctx[(b * 2048 + i0 + quad * 4 + r) * 256 + h * 32 + dt * 16 + l16] = f2b(o);
            }
    }
}

// ---------------------------------------------------------------------------
// kattn2: pure streaming attn writer. Recompute scores, scale by invl, store.
// Grid 2048 blocks = (bh, i-tile 64, j-half 1024); 4 waves x 16 rows x 16 jt.
// Validated mfma(Q,K) orientation (D row = i, col = j).
__global__ __launch_bounds__(256, 8) void kattn2(
    const unsigned short* __restrict__ q1w,  // [32][2048][32]
    const unsigned short* __restrict__ q2w,
    const unsigned short* __restrict__ kw,   // [32][2048][32]
    const unsigned short* __restrict__ rr,   // flat [8][2048][32]
    const float* __restrict__ mwf,           // [4][2048] f32 0/1
    const float* __restrict__ invl_ws,       // [32][2048] f32
    float* __restrict__ attn)                // [32][2048][2048] f32
{
    __shared__ __align__(16) float msk[1024];   // 4 KB (j-half mask)

    // bh-clustered XCD swizzle: XCD x owns bh 4x..4x+3 (256 blocks each)
    const int blk = blockIdx.x;              // 2048 = 32 bh * 32 it * 2 jh
    const int idx = blk >> 3;                // [0,256)
    const int bh = ((blk & 7) << 2) | (idx >> 6);
    const int rem = idx & 63;
    const int it = rem >> 1, jh = rem & 1;
    const int b = bh >> 3, h = bh & 7;
    const int tid = threadIdx.x;
    const int wid = tid >> 6, lane = tid & 63;
    const int l16 = lane & 15, quad = lane >> 4;
    const int i0 = it * 64 + wid * 16;
    const int jbase = jh * 1024;

    // stage j-half mask: 256 threads x 4
    *(f32x4*)&msk[tid * 4] = *(const f32x4*)(mwf + b * 2048 + jbase + tid * 4);
    __syncthreads();

    const bf16x8 a1 = *(const bf16x8*)(q1w + (bh * 2048 + i0 + l16) * 32 + quad * 8);
    const bf16x8 a2 = *(const bf16x8*)(q2w + (bh * 2048 + i0 + l16) * 32 + quad * 8);

    float scl[4], add[4];
#pragma unroll
    for (int r = 0; r < 4; ++r) {
        const int row = i0 + quad * 4 + r;
        const float iv = invl_ws[bh * 2048 + row];
        const float mi = mwf[b * 2048 + row];
        scl[r] = (mi == 0.f) ? 0.f : iv;   // v = exp2(s)*mj*scl + add
        add[r] = (mi == 0.f) ? iv  : 0.f;  // masked row -> uniform invl (=1/2048)
    }

    const unsigned short* kbase = kw + bh * 2048 * 32;
    const unsigned short* rbase = rr + h * 65536;
    float* abase = attn + (bh * 2048 + i0) * 2048;

    for (int jt = 0; jt < 16; ++jt) {
        const int jl = jt * 64;              // offset within j-half
        const int j0 = jbase + jl;           // global j
        f32x4 s[4];
#pragma unroll
        for (int t = 0; t < 4; ++t) {
            bf16x8 bK = *(const bf16x8*)(kbase + (j0 + t * 16 + l16) * 32 + quad * 8);
            bf16x8 bR = *(const bf16x8*)(rbase + (j0 + t * 16 + l16) * 32 + quad * 8);
            f32x4 z = {};
            z = __builtin_amdgcn_mfma_f32_16x16x32_bf16(a1, bK, z, 0, 0, 0);
            s[t] = __builtin_amdgcn_mfma_f32_16x16x32_bf16(a2, bR, z, 0, 0, 0);
        }
#pragma unroll
        for (int t = 0; t < 4; ++t) {
            const float mj = msk[jl + t * 16 + l16];
            float* dst = abase + j0 + t * 16 + l16 + (quad * 4) * 2048;
#pragma unroll
            for (int r = 0; r < 4; ++r) {
                float v = exp2_fast(s[t][r]) * mj * scl[r] + add[r];
                dst[r * 2048] = v;
            }
        }
    }
}

// ---------------------------------------------------------------------------
extern "C" void kernel_launch(void* const* d_in, const int* in_sizes, int n_in,
                              void* d_out, int out_size, void* d_ws, size_t ws_size,
                              hipStream_t stream) {
    const float* w    = (const float*)d_in[0];  // [4][2048][256]
    const float* r    = (const float*)d_in[1];  // [2048][256]
    const int*   am   = (const int*)d_in[2];    // [4][2047]
    const float* Wqkv = (const float*)d_in[3];  // [256][768]
    const float* Wr   = (const float*)d_in[4];  // [256][256]
    const float* Wout = (const float*)d_in[5];  // [256][256]
    const float* rwb  = (const float*)d_in[6];  // [8][1][32]
    const float* rrb  = (const float*)d_in[7];  // [8][1][32]

    float* out  = (float*)d_out;                // [4][2048][256] f32
    float* attn = out + 4 * 2048 * 256;         // [4][8][2048][2048] f32

    unsigned short* ws    = (unsigned short*)d_ws;          // ~27 MB scratch
    unsigned short* wb    = ws;                             // 2,097,152
    unsigned short* rb    = wb + 2097152;                   // 524,288
    unsigned short* q1w   = rb + 524288;                    // 2,097,152
    unsigned short* q2w   = q1w + 2097152;
    unsigned short* kw    = q2w + 2097152;
    unsigned short* vTw   = kw + 2097152;
    unsigned short* rrw   = vTw + 2097152;                  // 524,288
    unsigned short* ctx   = rrw + 524288;                   // 2,097,152
    unsigned short* WqkvT = ctx + 2097152;                  // 196,608
    unsigned short* WrT   = WqkvT + 196608;                 // 65,536
    unsigned short* WoutT = WrT + 65536;                    // 65,536
    float*          mwfp  = (float*)(WoutT + 65536);        // 8,192 f32 (32 KB)
    float*          invlp = mwfp + 8192;                    // 65,536 f32 (256 KB)

    kprep    <<<dim3(11552),   dim3(256), 0, stream>>>(w, r, Wqkv, Wr, Wout, am,
                                                       wb, rb, WqkvT, WrT, WoutT, mwfp);
    kqkv     <<<dim3(128, 12), dim3(256), 0, stream>>>(wb, WqkvT, rwb, rrb, q1w, q2w, kw, vTw);
    kgemm256b<<<dim3(32, 4),   dim3(256), 0, stream>>>(rb, WrT, rrw);
    kattn1   <<<dim3(2048),    dim3(256), 0, stream>>>(q1w, q2w, kw, vTw, rrw, mwfp, invlp, ctx);
    kattn2   <<<dim3(2048),    dim3(256), 0, stream>>>(q1w, q2w, kw, rrw, mwfp, invlp, attn);
    kgemm256f<<<dim3(128, 4),  dim3(256), 0, stream>>>(ctx, WoutT, out);
}